// Round 14
// baseline (240.547 us; speedup 1.0000x reference)
//
#include <hip/hip_runtime.h>
#include <hip/hip_bf16.h>

#define B_ 2
#define S_ 2048
#define H_ 2048
#define NH_ 16
#define NG_ 4
#define HD_ 128
#define HPG_ 4

typedef __attribute__((ext_vector_type(8))) short short8;
typedef __attribute__((ext_vector_type(4))) short short4v;
typedef __attribute__((ext_vector_type(4))) float float4v;

#define MFMA_BF16 __builtin_amdgcn_mfma_f32_16x16x32_bf16

#if __has_builtin(__builtin_amdgcn_exp2f)
#define EXP2(x) __builtin_amdgcn_exp2f(x)
#else
#define EXP2(x) exp2f(x)
#endif

// async global->LDS, 16B per lane. Per-lane lds ptr must equal wavebase + lane*16.
__device__ __forceinline__ void gload16(const void* g, void* l) {
    __builtin_amdgcn_global_load_lds(
        (const __attribute__((address_space(1))) unsigned int*)g,
        (__attribute__((address_space(3))) unsigned int*)l, 16, 0, 0);
}

__device__ __forceinline__ short bf16bits(float f) {
    union { __hip_bfloat16 h; short s; } u;
    u.h = __float2bfloat16(f);
    return u.s;
}

// ---------------- fused fp32 -> bf16 conversion + mask + bias concat ----------------
// chunk counts: hs 1048576, Wq 524288, Wk 131072, Wv 131072 -> total 1835008 = 7168*256
__global__ __launch_bounds__(256) void cvt_all(const float* __restrict__ hs,
                                               const float* __restrict__ wq,
                                               const float* __restrict__ wk,
                                               const float* __restrict__ wv,
                                               const int* __restrict__ mask,
                                               const float* __restrict__ bq,
                                               const float* __restrict__ bk,
                                               const float* __restrict__ bv,
                                               __hip_bfloat16* __restrict__ o_hs,
                                               __hip_bfloat16* __restrict__ o_wq,
                                               __hip_bfloat16* __restrict__ o_wk,
                                               __hip_bfloat16* __restrict__ o_wv,
                                               float* __restrict__ o_m,
                                               float* __restrict__ o_bc) {
    int i = blockIdx.x * 256 + threadIdx.x;
    if (blockIdx.x == 0) {
        // mask -> additive term (0 keep, -3e38 drop); exp2(-3e38) == 0
#pragma unroll
        for (int j = 0; j < 16; ++j) {
            int idx = threadIdx.x * 16 + j;
            o_m[idx] = mask[idx] ? 0.0f : -3.0e38f;
        }
    }
    if (blockIdx.x == 1) {
        // concatenated bias [3072] = bq | bk | bv
#pragma unroll
        for (int j = 0; j < 12; ++j) {
            int idx = j * 256 + threadIdx.x;
            float v = (idx < 2048) ? bq[idx] : (idx < 2560) ? bk[idx - 2048] : bv[idx - 2560];
            o_bc[idx] = v;
        }
    }
    const float* src;
    __hip_bfloat16* dst;
    int off;
    if (i < 1048576)      { src = hs; dst = o_hs; off = i; }
    else if (i < 1572864) { src = wq; dst = o_wq; off = i - 1048576; }
    else if (i < 1703936) { src = wk; dst = o_wk; off = i - 1572864; }
    else                  { src = wv; dst = o_wv; off = i - 1703936; }
    const float4* s4 = (const float4*)src;
    float4 a = s4[2 * (size_t)off];
    float4 b = s4[2 * (size_t)off + 1];
    union { short8 s; __hip_bfloat16 h[8]; } u;
    u.h[0] = __float2bfloat16(a.x); u.h[1] = __float2bfloat16(a.y);
    u.h[2] = __float2bfloat16(a.z); u.h[3] = __float2bfloat16(a.w);
    u.h[4] = __float2bfloat16(b.x); u.h[5] = __float2bfloat16(b.y);
    u.h[6] = __float2bfloat16(b.z); u.h[7] = __float2bfloat16(b.w);
    *(short8*)(dst + 8 * (size_t)off) = u.s;
}

// ---------------- fused q/k/v GEMM, 128x192 tile, BK=64, 2-phase, 2 blocks/CU ----------------
// r13 change (parameter-only on the verified r10 template): tile 256x192 -> 128x192 so
// LDS/buffer = (128+192)*64*2B = 40960, 2 buffers = 81920 B = EXACTLY 2 blocks/CU.
// Grid 512 = 32 bm x 16 bn = all co-resident at 2/CU. Mechanism (m114/m103): when one
// block's waves sit in the end-of-iter vmcnt(0)+barrier drain, the co-resident block's
// waves issue MFMA -- the cross-block overlap that m97/m103's 874-912 TF relied on and
// that 1-block/CU structurally excludes (r2/r10 both ~740 TF).
// Everything else identical to r10: BK=64, 2 barriers/tile, STAGE(t+1) issue-first,
// 5 uniform gloads/thread (A 2 rounds, B 3 rounds), chunk-XOR c'^(r&7) / read key x&7,
// k-accumulation tile-major kk-ascending (absmax preserved), wn*48 epilogue routing.
// XCD swizzle: 512 = 8 XCD x 64 consecutive ids, bn-major (2 B-panels = 1.5MB L2/XCD).
__global__ __launch_bounds__(512, 4) void gemm_qkv3(const __hip_bfloat16* __restrict__ A,
                                                    const __hip_bfloat16* __restrict__ Wcat,
                                                    const float* __restrict__ biasC,
                                                    __hip_bfloat16* __restrict__ qO,
                                                    __hip_bfloat16* __restrict__ kO,
                                                    __hip_bfloat16* __restrict__ vTO) {
    extern __shared__ char lds[];  // 81920 B = 2 x 40960

    const int tid = threadIdx.x;
    const int lane = tid & 63;
    const int x = lane & 15, g = lane >> 4;
    const int wid = tid >> 6;            // 0..7
    const int wm = wid >> 2, wn = wid & 3;

    const int id0 = blockIdx.x;                        // 0..511
    const int id = ((id0 & 7) << 6) | (id0 >> 3);      // bijective: 512 = 8 XCD x 64
    const int bn_t = id >> 5, bm_t = id & 31;          // bn-major within XCD
    const int bm = bm_t * 128, bn = bn_t * 192;

    // staging source: thread -> row (tid>>3) (+64 per round), stored chunk tid&7,
    // logical chunk schunk = (tid&7) ^ ((tid>>3)&7); global k-offset schunk*8.
    const int srow = tid >> 3;                         // 0..63
    const int schunk = (tid & 7) ^ (srow & 7);
    const __hip_bfloat16* gA = A + (size_t)(bm + srow) * 2048 + schunk * 8;
    const __hip_bfloat16* gB = Wcat + (size_t)(bn + srow) * 2048 + schunk * 8;

    // frag byte offsets within a buffer: A rows [0,128) at +0, B rows [0,192) at +16384;
    // row stride 128B, read chunk (kk*4+g)^(x&7)
    int aoff[4][2], boff[3][2];
#pragma unroll
    for (int mb = 0; mb < 4; ++mb)
#pragma unroll
        for (int kk = 0; kk < 2; ++kk)
            aoff[mb][kk] = (wm * 64 + mb * 16 + x) * 128 + (((kk * 4 + g) ^ (x & 7)) * 16);
#pragma unroll
    for (int nb = 0; nb < 3; ++nb)
#pragma unroll
        for (int kk = 0; kk < 2; ++kk)
            boff[nb][kk] = 16384 + (wn * 48 + nb * 16 + x) * 128 + (((kk * 4 + g) ^ (x & 7)) * 16);

    float4v acc[4][3];
#pragma unroll
    for (int i = 0; i < 4; ++i)
#pragma unroll
        for (int j = 0; j < 3; ++j) acc[i][j] = (float4v)0.f;

    // prologue: stage tile 0 -> buf 0 (A 2 rounds, B 3 rounds)
#pragma unroll
    for (int p = 0; p < 2; ++p)
        gload16(gA + (size_t)p * 131072, lds + p * 8192 + tid * 16);
#pragma unroll
    for (int p = 0; p < 3; ++p)
        gload16(gB + (size_t)p * 131072, lds + 16384 + p * 8192 + tid * 16);
    gA += 64; gB += 64;
    asm volatile("s_waitcnt vmcnt(0)" ::: "memory");
    __builtin_amdgcn_s_barrier();

    for (int t = 0; t < 32; ++t) {
        const char* cur = lds + (t & 1) * 40960;
        char* nxt = lds + ((t & 1) ^ 1) * 40960;

        // issue STAGE(t+1) first (T3 recipe) -- full compute phase covers the latency
        if (t < 31) {
#pragma unroll
            for (int p = 0; p < 2; ++p)
                gload16(gA + (size_t)p * 131072, nxt + p * 8192 + tid * 16);
#pragma unroll
            for (int p = 0; p < 3; ++p)
                gload16(gB + (size_t)p * 131072, nxt + 16384 + p * 8192 + tid * 16);
            gA += 64; gB += 64;
        }

        // kk = 0,1: ds_read frags then MFMA (compiler inserts fine-grained lgkmcnt)
#pragma unroll
        for (int kk = 0; kk < 2; ++kk) {
            short8 af[4], bf[3];
#pragma unroll
            for (int mb = 0; mb < 4; ++mb) af[mb] = *(const short8*)(cur + aoff[mb][kk]);
#pragma unroll
            for (int nb = 0; nb < 3; ++nb) bf[nb] = *(const short8*)(cur + boff[nb][kk]);
            __builtin_amdgcn_s_setprio(1);
#pragma unroll
            for (int mb = 0; mb < 4; ++mb)
#pragma unroll
                for (int nb = 0; nb < 3; ++nb)
                    acc[mb][nb] = MFMA_BF16(af[mb], bf[nb], acc[mb][nb], 0, 0, 0);
            __builtin_amdgcn_s_setprio(0);
        }

        // t+1 resident for next iter; cur's reads already retired (consumed by MFMA).
        // The drain stall is hidden by the co-resident second block's compute (m114).
        asm volatile("s_waitcnt vmcnt(0)" ::: "memory");
        __builtin_amdgcn_s_barrier();
    }

    // epilogue: per-frag routing Q / K / V^T (16-col frags never straddle 2048/2560)
#pragma unroll
    for (int mb = 0; mb < 4; ++mb) {
#pragma unroll
        for (int nb = 0; nb < 3; ++nb) {
            const int n = bn + wn * 48 + nb * 16 + x;
            const float bsv = biasC[n];
            const int m0 = bm + wm * 64 + mb * 16 + g * 4;
            if (n < 2048) {
#pragma unroll
                for (int r = 0; r < 4; ++r)
                    qO[(size_t)(m0 + r) * 2048 + n] = __float2bfloat16(acc[mb][nb][r] + bsv);
            } else if (n < 2560) {
                const int nk = n - 2048;
#pragma unroll
                for (int r = 0; r < 4; ++r)
                    kO[(size_t)(m0 + r) * 512 + nk] = __float2bfloat16(acc[mb][nb][r] + bsv);
            } else {
                const int nv = n - 2560;
                const int gv = nv >> 7, d = nv & 127;
                const int bb2 = m0 >> 11, s = m0 & 2047;
                short4v pk;
#pragma unroll
                for (int r = 0; r < 4; ++r) pk[r] = bf16bits(acc[mb][nb][r] + bsv);
                *(short4v*)(vTO + ((size_t)(bb2 * NG_ + gv) * HD_ + d) * S_ + s) = pk;
            }
        }
    }
}

// ---------------- Flash attention, QBLK=256, r6 structure + Ks dbuf / alpha K-issue ----------------
// (unchanged from round 9 -- verified ~81us; attn plateaued, see r8/r9 post-mortems)
__global__ __launch_bounds__(512, 2) void attn(const __hip_bfloat16* __restrict__ q,
                                               const __hip_bfloat16* __restrict__ k,
                                               const __hip_bfloat16* __restrict__ vT,
                                               const float* __restrict__ M,
                                               float* __restrict__ out) {
    extern __shared__ char smem[];  // 83968
    char* Ks = smem;                // 2 x 16384   [t=64][d=128] chunk-xor
    char* Vs = smem + 32768;        // 16384       [d=128][t=64] chunk-xor
    char* Ps = smem + 49152;        // 34816       [q=256] rows of 136B (0-conflict)

    const int tid = threadIdx.x;
    const int lane = tid & 63;
    const int w = tid >> 6;          // 0..7
    const int wm = w >> 2, wn = w & 3;
    const int x = lane & 15, g = lane >> 4;

    // XCD-aware swizzle: 256 blocks = 8 XCDs x 32; XCD xcd = (b<<2)|gi owns its KV slice.
    const int bid0 = blockIdx.x;
    const int bid = ((bid0 & 7) << 5) | (bid0 >> 3);
    const int qt = bid & 7;
    const int hp = (bid >> 3) & 3;
    const int gi = (bid >> 5) & 3;
    const int b = bid >> 7;
    const int head = gi * HPG_ + hp;
    const int q0 = qt * 256;

    // Q B-frags in registers: B[k=d][n=q]: n = wn*64+nb*16+x, k = ks*32+g*8+j
    short8 qf[4][4];
#pragma unroll
    for (int nb = 0; nb < 4; ++nb) {
        const int qq = q0 + wn * 64 + nb * 16 + x;
        const __hip_bfloat16* qrow = q + ((size_t)(b * S_ + qq) * NH_ + head) * HD_ + g * 8;
#pragma unroll
        for (int ks = 0; ks < 4; ++ks)
            qf[nb][ks] = *(const short8*)(qrow + ks * 32);
    }

    // K staging (512 thr, 2 rounds): dest row (tid>>4)+{0,32}, chunk tid&15; src chunk ^(row&15)
    const int kchunk = (tid & 15) ^ ((tid >> 4) & 15);
    const __hip_bfloat16* kp = k + ((size_t)(b * S_ + (tid >> 4)) * NG_ + gi) * HD_ + kchunk * 8;
    // V staging (2 rounds): dest d-row (tid>>3)+{0,64}, chunk tid&7; src chunk ^(row&7)
    const int vchunk = (tid & 7) ^ ((tid >> 3) & 7);
    const __hip_bfloat16* vp = vT + ((size_t)(b * NG_ + gi) * HD_ + (tid >> 3)) * S_ + vchunk * 8;
    const float* mp = M + b * S_ + wm * 32 + g * 4;

    float4v O[4][4];
#pragma unroll
    for (int i = 0; i < 4; ++i)
#pragma unroll
        for (int j = 0; j < 4; ++j) O[i][j] = (float4v)0.f;
    float l_part[4] = {0.f, 0.f, 0.f, 0.f};

    const float SM = 0.08838834764831845f * 1.4426950408889634f;  // scale * log2(e)

    // prologue: issue K(0) -> Ks[0]
    gload16(kp, Ks + tid * 16);
    gload16(kp + 16384, Ks + tid * 16 + 8192);
    kp += 32768;  // next K tile (t advances 64 rows x 512 elem)

    for (int it = 0; it < 32; ++it) {
        __syncthreads();  // alpha: K(it) resident; PV(it-1) closed -> Vs, Ps free
        const int p = it & 1;
        const char* KsC = Ks + p * 16384;

        float4 mv0 = *(const float4*)(mp);
        float4 mv1 = *(const float4*)(mp + 16);
        mp += 64;
        // issue V(it): d-rows 0..63 and 64..127 (+64 d-rows = +131072 elem in vT)
        gload16(vp, Vs + tid * 16);
        gload16(vp + 131072, Vs + tid * 16 + 8192);
        vp += 64;
        // issue K(it+1) -> Ks[p^1]; last reader QK(it-1) finished before alpha(it)
        if (it < 31) {
            char* KsN = Ks + (p ^ 1) * 16384;
            gload16(kp, KsN + tid * 16);
            gload16(kp + 16384, KsN + tid * 16 + 8192);
            kp += 32768;
        }

        // QK^T: wave t-rows [wm*32,+32), q-cols [wn*64,+64)
        float4v sc[2][4];
#pragma unroll
        for (int i = 0; i < 2; ++i)
#pragma unroll
            for (int j = 0; j < 4; ++j) sc[i][j] = (float4v)0.f;
        __builtin_amdgcn_s_setprio(1);
#pragma unroll
        for (int ks = 0; ks < 4; ++ks) {
            short8 af0 = *(const short8*)(KsC + (wm * 32 + x) * 256 + (((ks * 4 + g) ^ x) * 16));
            short8 af1 = *(const short8*)(KsC + (wm * 32 + 16 + x) * 256 + (((ks * 4 + g) ^ x) * 16));
#pragma unroll
            for (int nb = 0; nb < 4; ++nb) {
                sc[0][nb] = MFMA_BF16(af0, qf[nb][ks], sc[0][nb], 0, 0, 0);
                sc[1][nb] = MFMA_BF16(af1, qf[nb][ks], sc[1][nb], 0, 0, 0);
            }
        }
        __builtin_amdgcn_s_setprio(0);

        // softmax numerator: p = exp2(s*SM + madd); b64 P writes (136B stride, 0-conflict)
#pragma unroll
        for (int mb = 0; mb < 2; ++mb) {
            const float4 mv = mb ? mv1 : mv0;
            const int hs = wm * 8 + mb * 4 + g;  // t-halfslot 0..15
#pragma unroll
            for (int nb = 0; nb < 4; ++nb) {
                float p0 = EXP2(fmaf(sc[mb][nb][0], SM, mv.x));
                float p1 = EXP2(fmaf(sc[mb][nb][1], SM, mv.y));
                float p2 = EXP2(fmaf(sc[mb][nb][2], SM, mv.z));
                float p3 = EXP2(fmaf(sc[mb][nb][3], SM, mv.w));
                l_part[nb] += (p0 + p1) + (p2 + p3);
                short4v pk;
                pk[0] = bf16bits(p0); pk[1] = bf16bits(p1);
                pk[2] = bf16bits(p2); pk[3] = bf16bits(p3);
                *(short4v*)(Ps + (wn * 64 + nb * 16 + x) * 136 + hs * 8) = pk;
            }
        }

        __syncthreads();  // beta: P published; V(it), K(it+1) drained (covered by QK+SM)

        // PV: O^T[d-rows wm*64+64][q-cols wn*64+64] += V^T * P
#pragma unroll
        for (int ks = 0; ks < 2; ++ks) {
            short8 vf[4], pf[4];
#pragma unroll
            for (int i4 = 0; i4 < 4; ++i4) {
                vf[i4] = *(const short8*)(Vs + (wm * 64 + i4 * 16 + x) * 128 +
                                          (((ks * 4 + g) ^ (x & 7)) * 16));
                const char* pb = Ps + (wn * 64 + i4 * 16 + x) * 136 + (8 * ks + 2 * g) * 8;
                union { short4v h[2]; short8 s8; } uu;
                uu.h[0] = *(const short4v*)pb;
                uu.h[1] = *(const short4v*)(pb + 8);
                pf[i4] = uu.s8;
            }
            __builtin_amdgcn_s_setprio(1);
#pragma unroll
            for (int mb = 0; mb < 4; ++mb)
#pragma unroll
                for (int nb = 0; nb < 4; ++nb)
                    O[mb][nb] = MFMA_BF16(vf[mb], pf[nb], O[mb][nb], 0, 0, 0);
            __builtin_amdgcn_s_setprio(0);
        }
    }

    // final l reduction: over g (shuffles), then across wm pair (LDS)
    __syncthreads();
#pragma unroll
    for (int nb = 0; nb < 4; ++nb) {
        l_part[nb] += __shfl_xor(l_part[nb], 16);
        l_part[nb] += __shfl_xor(l_part[nb], 32);
    }
    float* lws = (float*)Ps;
    if (g == 0) {
#pragma unroll
        for (int nb = 0; nb < 4; ++nb)
            lws[wm * 256 + wn * 64 + nb * 16 + x] = l_part[nb];
    }
    __syncthreads();
    float inv[4];
#pragma unroll
    for (int nb = 0; nb < 4; ++nb)
        inv[nb] = 1.0f / (l_part[nb] + lws[(wm ^ 1) * 256 + wn * 64 + nb * 16 + x]);

    // epilogue: out[b, q0+q, head*128 + d]; reg r -> consecutive d -> float4 stores
#pragma unroll
    for (int mb = 0; mb < 4; ++mb) {
#pragma unroll
        for (int nb = 0; nb < 4; ++nb) {
            const int qq = q0 + wn * 64 + nb * 16 + x;
            const int d0 = wm * 64 + mb * 16 + g * 4;
            float4v o = O[mb][nb] * inv[nb];
            *(float4v*)(out + (size_t)(b * S_ + qq) * H_ + head * HD_ + d0) = o;
        }
    }
}

extern "C" void kernel_launch(void* const* d_in, const int* in_sizes, int n_in,
                              void* d_out, int out_size, void* d_ws, size_t ws_size,
                              hipStream_t stream) {
    (void)in_sizes; (void)n_in; (void)out_size; (void)ws_size;
    const float* hs = (const float*)d_in[0];
    const int* amask = (const int*)d_in[1];
    const float* Wq = (const float*)d_in[2];
    const float* bq = (const float*)d_in[3];
    const float* Wk = (const float*)d_in[4];
    const float* bk = (const float*)d_in[5];
    const float* Wv = (const float*)d_in[6];
    const float* bv = (const float*)d_in[7];
    float* out = (float*)d_out;

    char* ws = (char*)d_ws;
    __hip_bfloat16* hsB = (__hip_bfloat16*)(ws);              // 16 MB
    __hip_bfloat16* WqB = (__hip_bfloat16*)(ws + 16777216);   // 8 MB  -- Wq|Wk|Wv contiguous = Wcat [3072][2048]
    __hip_bfloat16* WkB = (__hip_bfloat16*)(ws + 25165824);   // 2 MB
    __hip_bfloat16* WvB = (__hip_bfloat16*)(ws + 27262976);   // 2 MB
    __hip_bfloat16* qB  = (__hip_bfloat16*)(ws + 29360128);   // 16 MB  [B,S,NH,HD]
    __hip_bfloat16* kB  = (__hip_bfloat16*)(ws + 46137344);   // 4 MB   [B,S,NG,HD]
    __hip_bfloat16* vTB = (__hip_bfloat16*)(ws + 50331648);   // 4 MB   [B,NG,HD,S]
    float* Mf           = (float*)(ws + 54525952);            // 16 KB  mask additive term
    float* biasC        = (float*)(ws + 54542336);            // 12 KB  bias concat [3072]

    hipFuncSetAttribute((const void*)gemm_qkv3,
                        hipFuncAttributeMaxDynamicSharedMemorySize, 81920);
    hipFuncSetAttribute((const void*)attn,
                        hipFuncAttributeMaxDynamicSharedMemorySize, 83968);

    cvt_all<<<7168, 256, 0, stream>>>(hs, Wq, Wk, Wv, amask, bq, bk, bv,
                                      hsB, WqB, WkB, WvB, Mf, biasC);
    gemm_qkv3<<<512, 512, 81920, stream>>>(hsB, WqB, biasC, qB, kB, vTB);
    attn<<<256, 512, 83968, stream>>>(qB, kB, vTB, Mf, out);
}

// Round 15
// 226.944 us; speedup vs baseline: 1.0599x; 1.0599x over previous
//
#include <hip/hip_runtime.h>
#include <hip/hip_bf16.h>

#define B_ 2
#define S_ 2048
#define H_ 2048
#define NH_ 16
#define NG_ 4
#define HD_ 128
#define HPG_ 4

typedef __attribute__((ext_vector_type(8))) short short8;
typedef __attribute__((ext_vector_type(4))) short short4v;
typedef __attribute__((ext_vector_type(4))) float float4v;

#define MFMA_BF16 __builtin_amdgcn_mfma_f32_16x16x32_bf16

#if __has_builtin(__builtin_amdgcn_exp2f)
#define EXP2(x) __builtin_amdgcn_exp2f(x)
#else
#define EXP2(x) exp2f(x)
#endif

// async global->LDS, 16B per lane. Per-lane lds ptr must equal wavebase + lane*16.
__device__ __forceinline__ void gload16(const void* g, void* l) {
    __builtin_amdgcn_global_load_lds(
        (const __attribute__((address_space(1))) unsigned int*)g,
        (__attribute__((address_space(3))) unsigned int*)l, 16, 0, 0);
}

__device__ __forceinline__ short bf16bits(float f) {
    union { __hip_bfloat16 h; short s; } u;
    u.h = __float2bfloat16(f);
    return u.s;
}

// ---------------- fused fp32 -> bf16 conversion + mask + bias concat ----------------
// chunk counts: hs 1048576, Wq 524288, Wk 131072, Wv 131072 -> total 1835008 = 7168*256
__global__ __launch_bounds__(256) void cvt_all(const float* __restrict__ hs,
                                               const float* __restrict__ wq,
                                               const float* __restrict__ wk,
                                               const float* __restrict__ wv,
                                               const int* __restrict__ mask,
                                               const float* __restrict__ bq,
                                               const float* __restrict__ bk,
                                               const float* __restrict__ bv,
                                               __hip_bfloat16* __restrict__ o_hs,
                                               __hip_bfloat16* __restrict__ o_wq,
                                               __hip_bfloat16* __restrict__ o_wk,
                                               __hip_bfloat16* __restrict__ o_wv,
                                               float* __restrict__ o_m,
                                               float* __restrict__ o_bc) {
    int i = blockIdx.x * 256 + threadIdx.x;
    if (blockIdx.x == 0) {
        // mask -> additive term (0 keep, -3e38 drop); exp2(-3e38) == 0
#pragma unroll
        for (int j = 0; j < 16; ++j) {
            int idx = threadIdx.x * 16 + j;
            o_m[idx] = mask[idx] ? 0.0f : -3.0e38f;
        }
    }
    if (blockIdx.x == 1) {
        // concatenated bias [3072] = bq | bk | bv
#pragma unroll
        for (int j = 0; j < 12; ++j) {
            int idx = j * 256 + threadIdx.x;
            float v = (idx < 2048) ? bq[idx] : (idx < 2560) ? bk[idx - 2048] : bv[idx - 2560];
            o_bc[idx] = v;
        }
    }
    const float* src;
    __hip_bfloat16* dst;
    int off;
    if (i < 1048576)      { src = hs; dst = o_hs; off = i; }
    else if (i < 1572864) { src = wq; dst = o_wq; off = i - 1048576; }
    else if (i < 1703936) { src = wk; dst = o_wk; off = i - 1572864; }
    else                  { src = wv; dst = o_wv; off = i - 1703936; }
    const float4* s4 = (const float4*)src;
    float4 a = s4[2 * (size_t)off];
    float4 b = s4[2 * (size_t)off + 1];
    union { short8 s; __hip_bfloat16 h[8]; } u;
    u.h[0] = __float2bfloat16(a.x); u.h[1] = __float2bfloat16(a.y);
    u.h[2] = __float2bfloat16(a.z); u.h[3] = __float2bfloat16(a.w);
    u.h[4] = __float2bfloat16(b.x); u.h[5] = __float2bfloat16(b.y);
    u.h[6] = __float2bfloat16(b.z); u.h[7] = __float2bfloat16(b.w);
    *(short8*)(dst + 8 * (size_t)off) = u.s;
}

// ---------------- fused q/k/v GEMM, 256x192 tile, BK=64, minimum-2-phase ----------------
// (r10/r13 verified source -- best measured config: totals 226.99 / 229.25 us.
// Measured-worse alternatives: 4-barrier BK=32 counted-vmcnt (r2, equal); m201 8-phase port
// (r12: 111us, MfmaUtil 18%, 3x HBM over-fetch); 128x192 2-blocks/CU (r14: +11us total,
// doubled B staging). This 2-phase 1-block/CU form is the practical plateau.)
// BK=64, 2 LDS buffers, 2 barriers/tile, 48 MFMA between drains. Per iter:
// STAGE(t+1, issue-first) -> ds_read/MFMA kk=0 -> ds_read/MFMA kk=1 -> vmcnt(0) -> barrier.
// Staging: 7 uniform gloads/thread. LDS per buffer (57344B): A [256][64] rows of 128B at
// +0, B [192][64] at +32768. Chunk-XOR: stored chunk c' at row r holds logical c'^(r&7);
// read key r&7 == x&7 (2-way banks = free). XCD swizzle bn-major; grid 256 = 1 block/CU.
__global__ __launch_bounds__(512, 2) void gemm_qkv3(const __hip_bfloat16* __restrict__ A,
                                                    const __hip_bfloat16* __restrict__ Wcat,
                                                    const float* __restrict__ biasC,
                                                    __hip_bfloat16* __restrict__ qO,
                                                    __hip_bfloat16* __restrict__ kO,
                                                    __hip_bfloat16* __restrict__ vTO) {
    extern __shared__ char lds[];  // 114688 B = 2 x 57344

    const int tid = threadIdx.x;
    const int lane = tid & 63;
    const int x = lane & 15, g = lane >> 4;
    const int wid = tid >> 6;            // 0..7
    const int wm = wid >> 2, wn = wid & 3;

    const int id0 = blockIdx.x;
    const int id = ((id0 & 7) << 5) | (id0 >> 3);
    const int bn_t = id >> 4, bm_t = id & 15;
    const int bm = bm_t * 256, bn = bn_t * 192;

    // staging source: thread -> row (tid>>3) (+64 per round), stored chunk tid&7,
    // logical chunk schunk = (tid&7) ^ ((tid>>3)&7); global k-offset schunk*8.
    const int srow = tid >> 3;                         // 0..63
    const int schunk = (tid & 7) ^ (srow & 7);
    const __hip_bfloat16* gA = A + (size_t)(bm + srow) * 2048 + schunk * 8;
    const __hip_bfloat16* gB = Wcat + (size_t)(bn + srow) * 2048 + schunk * 8;

    // frag byte offsets within a buffer: row stride 128B, read chunk (kk*4+g)^(x&7)
    int aoff[8][2], boff[3][2];
#pragma unroll
    for (int mb = 0; mb < 8; ++mb)
#pragma unroll
        for (int kk = 0; kk < 2; ++kk)
            aoff[mb][kk] = (wm * 128 + mb * 16 + x) * 128 + (((kk * 4 + g) ^ (x & 7)) * 16);
#pragma unroll
    for (int nb = 0; nb < 3; ++nb)
#pragma unroll
        for (int kk = 0; kk < 2; ++kk)
            boff[nb][kk] = 32768 + (wn * 48 + nb * 16 + x) * 128 + (((kk * 4 + g) ^ (x & 7)) * 16);

    float4v acc[8][3];
#pragma unroll
    for (int i = 0; i < 8; ++i)
#pragma unroll
        for (int j = 0; j < 3; ++j) acc[i][j] = (float4v)0.f;

    // prologue: stage tile 0 -> buf 0
#pragma unroll
    for (int p = 0; p < 4; ++p)
        gload16(gA + (size_t)p * 131072, lds + p * 8192 + tid * 16);
#pragma unroll
    for (int p = 0; p < 3; ++p)
        gload16(gB + (size_t)p * 131072, lds + 32768 + p * 8192 + tid * 16);
    gA += 64; gB += 64;
    asm volatile("s_waitcnt vmcnt(0)" ::: "memory");
    __builtin_amdgcn_s_barrier();

    for (int t = 0; t < 32; ++t) {
        const char* cur = lds + (t & 1) * 57344;
        char* nxt = lds + ((t & 1) ^ 1) * 57344;

        // issue STAGE(t+1) first (T3 recipe) -- full compute phase covers the latency
        if (t < 31) {
#pragma unroll
            for (int p = 0; p < 4; ++p)
                gload16(gA + (size_t)p * 131072, nxt + p * 8192 + tid * 16);
#pragma unroll
            for (int p = 0; p < 3; ++p)
                gload16(gB + (size_t)p * 131072, nxt + 32768 + p * 8192 + tid * 16);
            gA += 64; gB += 64;
        }

        // kk = 0,1: ds_read frags then MFMA (compiler inserts fine-grained lgkmcnt)
#pragma unroll
        for (int kk = 0; kk < 2; ++kk) {
            short8 af[8], bf[3];
#pragma unroll
            for (int mb = 0; mb < 8; ++mb) af[mb] = *(const short8*)(cur + aoff[mb][kk]);
#pragma unroll
            for (int nb = 0; nb < 3; ++nb) bf[nb] = *(const short8*)(cur + boff[nb][kk]);
            __builtin_amdgcn_s_setprio(1);
#pragma unroll
            for (int mb = 0; mb < 8; ++mb)
#pragma unroll
                for (int nb = 0; nb < 3; ++nb)
                    acc[mb][nb] = MFMA_BF16(af[mb], bf[nb], acc[mb][nb], 0, 0, 0);
            __builtin_amdgcn_s_setprio(0);
        }

        // t+1 resident for next iter; cur's reads already retired (consumed by MFMA)
        asm volatile("s_waitcnt vmcnt(0)" ::: "memory");
        __builtin_amdgcn_s_barrier();
    }

    // epilogue: per-frag routing Q / K / V^T (16-col frags never straddle 2048/2560)
#pragma unroll
    for (int mb = 0; mb < 8; ++mb) {
#pragma unroll
        for (int nb = 0; nb < 3; ++nb) {
            const int n = bn + wn * 48 + nb * 16 + x;
            const float bsv = biasC[n];
            const int m0 = bm + wm * 128 + mb * 16 + g * 4;
            if (n < 2048) {
#pragma unroll
                for (int r = 0; r < 4; ++r)
                    qO[(size_t)(m0 + r) * 2048 + n] = __float2bfloat16(acc[mb][nb][r] + bsv);
            } else if (n < 2560) {
                const int nk = n - 2048;
#pragma unroll
                for (int r = 0; r < 4; ++r)
                    kO[(size_t)(m0 + r) * 512 + nk] = __float2bfloat16(acc[mb][nb][r] + bsv);
            } else {
                const int nv = n - 2560;
                const int gv = nv >> 7, d = nv & 127;
                const int bb2 = m0 >> 11, s = m0 & 2047;
                short4v pk;
#pragma unroll
                for (int r = 0; r < 4; ++r) pk[r] = bf16bits(acc[mb][nb][r] + bsv);
                *(short4v*)(vTO + ((size_t)(bb2 * NG_ + gv) * HD_ + d) * S_ + s) = pk;
            }
        }
    }
}

// ---------------- Flash attention, QBLK=256, r6 structure + Ks dbuf / alpha K-issue ----------------
// (unchanged from round 9 -- verified ~81us; attn plateaued, see r8/r9 post-mortems)
__global__ __launch_bounds__(512, 2) void attn(const __hip_bfloat16* __restrict__ q,
                                               const __hip_bfloat16* __restrict__ k,
                                               const __hip_bfloat16* __restrict__ vT,
                                               const float* __restrict__ M,
                                               float* __restrict__ out) {
    extern __shared__ char smem[];  // 83968
    char* Ks = smem;                // 2 x 16384   [t=64][d=128] chunk-xor
    char* Vs = smem + 32768;        // 16384       [d=128][t=64] chunk-xor
    char* Ps = smem + 49152;        // 34816       [q=256] rows of 136B (0-conflict)

    const int tid = threadIdx.x;
    const int lane = tid & 63;
    const int w = tid >> 6;          // 0..7
    const int wm = w >> 2, wn = w & 3;
    const int x = lane & 15, g = lane >> 4;

    // XCD-aware swizzle: 256 blocks = 8 XCDs x 32; XCD xcd = (b<<2)|gi owns its KV slice.
    const int bid0 = blockIdx.x;
    const int bid = ((bid0 & 7) << 5) | (bid0 >> 3);
    const int qt = bid & 7;
    const int hp = (bid >> 3) & 3;
    const int gi = (bid >> 5) & 3;
    const int b = bid >> 7;
    const int head = gi * HPG_ + hp;
    const int q0 = qt * 256;

    // Q B-frags in registers: B[k=d][n=q]: n = wn*64+nb*16+x, k = ks*32+g*8+j
    short8 qf[4][4];
#pragma unroll
    for (int nb = 0; nb < 4; ++nb) {
        const int qq = q0 + wn * 64 + nb * 16 + x;
        const __hip_bfloat16* qrow = q + ((size_t)(b * S_ + qq) * NH_ + head) * HD_ + g * 8;
#pragma unroll
        for (int ks = 0; ks < 4; ++ks)
            qf[nb][ks] = *(const short8*)(qrow + ks * 32);
    }

    // K staging (512 thr, 2 rounds): dest row (tid>>4)+{0,32}, chunk tid&15; src chunk ^(row&15)
    const int kchunk = (tid & 15) ^ ((tid >> 4) & 15);
    const __hip_bfloat16* kp = k + ((size_t)(b * S_ + (tid >> 4)) * NG_ + gi) * HD_ + kchunk * 8;
    // V staging (2 rounds): dest d-row (tid>>3)+{0,64}, chunk tid&7; src chunk ^(row&7)
    const int vchunk = (tid & 7) ^ ((tid >> 3) & 7);
    const __hip_bfloat16* vp = vT + ((size_t)(b * NG_ + gi) * HD_ + (tid >> 3)) * S_ + vchunk * 8;
    const float* mp = M + b * S_ + wm * 32 + g * 4;

    float4v O[4][4];
#pragma unroll
    for (int i = 0; i < 4; ++i)
#pragma unroll
        for (int j = 0; j < 4; ++j) O[i][j] = (float4v)0.f;
    float l_part[4] = {0.f, 0.f, 0.f, 0.f};

    const float SM = 0.08838834764831845f * 1.4426950408889634f;  // scale * log2(e)

    // prologue: issue K(0) -> Ks[0]
    gload16(kp, Ks + tid * 16);
    gload16(kp + 16384, Ks + tid * 16 + 8192);
    kp += 32768;  // next K tile (t advances 64 rows x 512 elem)

    for (int it = 0; it < 32; ++it) {
        __syncthreads();  // alpha: K(it) resident; PV(it-1) closed -> Vs, Ps free
        const int p = it & 1;
        const char* KsC = Ks + p * 16384;

        float4 mv0 = *(const float4*)(mp);
        float4 mv1 = *(const float4*)(mp + 16);
        mp += 64;
        // issue V(it): d-rows 0..63 and 64..127 (+64 d-rows = +131072 elem in vT)
        gload16(vp, Vs + tid * 16);
        gload16(vp + 131072, Vs + tid * 16 + 8192);
        vp += 64;
        // issue K(it+1) -> Ks[p^1]; last reader QK(it-1) finished before alpha(it)
        if (it < 31) {
            char* KsN = Ks + (p ^ 1) * 16384;
            gload16(kp, KsN + tid * 16);
            gload16(kp + 16384, KsN + tid * 16 + 8192);
            kp += 32768;
        }

        // QK^T: wave t-rows [wm*32,+32), q-cols [wn*64,+64)
        float4v sc[2][4];
#pragma unroll
        for (int i = 0; i < 2; ++i)
#pragma unroll
            for (int j = 0; j < 4; ++j) sc[i][j] = (float4v)0.f;
        __builtin_amdgcn_s_setprio(1);
#pragma unroll
        for (int ks = 0; ks < 4; ++ks) {
            short8 af0 = *(const short8*)(KsC + (wm * 32 + x) * 256 + (((ks * 4 + g) ^ x) * 16));
            short8 af1 = *(const short8*)(KsC + (wm * 32 + 16 + x) * 256 + (((ks * 4 + g) ^ x) * 16));
#pragma unroll
            for (int nb = 0; nb < 4; ++nb) {
                sc[0][nb] = MFMA_BF16(af0, qf[nb][ks], sc[0][nb], 0, 0, 0);
                sc[1][nb] = MFMA_BF16(af1, qf[nb][ks], sc[1][nb], 0, 0, 0);
            }
        }
        __builtin_amdgcn_s_setprio(0);

        // softmax numerator: p = exp2(s*SM + madd); b64 P writes (136B stride, 0-conflict)
#pragma unroll
        for (int mb = 0; mb < 2; ++mb) {
            const float4 mv = mb ? mv1 : mv0;
            const int hs = wm * 8 + mb * 4 + g;  // t-halfslot 0..15
#pragma unroll
            for (int nb = 0; nb < 4; ++nb) {
                float p0 = EXP2(fmaf(sc[mb][nb][0], SM, mv.x));
                float p1 = EXP2(fmaf(sc[mb][nb][1], SM, mv.y));
                float p2 = EXP2(fmaf(sc[mb][nb][2], SM, mv.z));
                float p3 = EXP2(fmaf(sc[mb][nb][3], SM, mv.w));
                l_part[nb] += (p0 + p1) + (p2 + p3);
                short4v pk;
                pk[0] = bf16bits(p0); pk[1] = bf16bits(p1);
                pk[2] = bf16bits(p2); pk[3] = bf16bits(p3);
                *(short4v*)(Ps + (wn * 64 + nb * 16 + x) * 136 + hs * 8) = pk;
            }
        }

        __syncthreads();  // beta: P published; V(it), K(it+1) drained (covered by QK+SM)

        // PV: O^T[d-rows wm*64+64][q-cols wn*64+64] += V^T * P
#pragma unroll
        for (int ks = 0; ks < 2; ++ks) {
            short8 vf[4], pf[4];
#pragma unroll
            for (int i4 = 0; i4 < 4; ++i4) {
                vf[i4] = *(const short8*)(Vs + (wm * 64 + i4 * 16 + x) * 128 +
                                          (((ks * 4 + g) ^ (x & 7)) * 16));
                const char* pb = Ps + (wn * 64 + i4 * 16 + x) * 136 + (8 * ks + 2 * g) * 8;
                union { short4v h[2]; short8 s8; } uu;
                uu.h[0] = *(const short4v*)pb;
                uu.h[1] = *(const short4v*)(pb + 8);
                pf[i4] = uu.s8;
            }
            __builtin_amdgcn_s_setprio(1);
#pragma unroll
            for (int mb = 0; mb < 4; ++mb)
#pragma unroll
                for (int nb = 0; nb < 4; ++nb)
                    O[mb][nb] = MFMA_BF16(vf[mb], pf[nb], O[mb][nb], 0, 0, 0);
            __builtin_amdgcn_s_setprio(0);
        }
    }

    // final l reduction: over g (shuffles), then across wm pair (LDS)
    __syncthreads();
#pragma unroll
    for (int nb = 0; nb < 4; ++nb) {
        l_part[nb] += __shfl_xor(l_part[nb], 16);
        l_part[nb] += __shfl_xor(l_part[nb], 32);
    }
    float* lws = (float*)Ps;
    if (g == 0) {
#pragma unroll
        for (int nb = 0; nb < 4; ++nb)
            lws[wm * 256 + wn * 64 + nb * 16 + x] = l_part[nb];
    }
    __syncthreads();
    float inv[4];
#pragma unroll
    for (int nb = 0; nb < 4; ++nb)
        inv[nb] = 1.0f / (l_part[nb] + lws[(wm ^ 1) * 256 + wn * 64 + nb * 16 + x]);

    // epilogue: out[b, q0+q, head*128 + d]; reg r -> consecutive d -> float4 stores
#pragma unroll
    for (int mb = 0; mb < 4; ++mb) {
#pragma unroll
        for (int nb = 0; nb < 4; ++nb) {
            const int qq = q0 + wn * 64 + nb * 16 + x;
            const int d0 = wm * 64 + mb * 16 + g * 4;
            float4v o = O[mb][nb] * inv[nb];
            *(float4v*)(out + (size_t)(b * S_ + qq) * H_ + head * HD_ + d0) = o;
        }
    }
}

extern "C" void kernel_launch(void* const* d_in, const int* in_sizes, int n_in,
                              void* d_out, int out_size, void* d_ws, size_t ws_size,
                              hipStream_t stream) {
    (void)in_sizes; (void)n_in; (void)out_size; (void)ws_size;
    const float* hs = (const float*)d_in[0];
    const int* amask = (const int*)d_in[1];
    const float* Wq = (const float*)d_in[2];
    const float* bq = (const float*)d_in[3];
    const float* Wk = (const float*)d_in[4];
    const float* bk = (const float*)d_in[5];
    const float* Wv = (const float*)d_in[6];
    const float* bv = (const float*)d_in[7];
    float* out = (float*)d_out;

    char* ws = (char*)d_ws;
    __hip_bfloat16* hsB = (__hip_bfloat16*)(ws);              // 16 MB
    __hip_bfloat16* WqB = (__hip_bfloat16*)(ws + 16777216);   // 8 MB  -- Wq|Wk|Wv contiguous = Wcat [3072][2048]
    __hip_bfloat16* WkB = (__hip_bfloat16*)(ws + 25165824);   // 2 MB
    __hip_bfloat16* WvB = (__hip_bfloat16*)(ws + 27262976);   // 2 MB
    __hip_bfloat16* qB  = (__hip_bfloat16*)(ws + 29360128);   // 16 MB  [B,S,NH,HD]
    __hip_bfloat16* kB  = (__hip_bfloat16*)(ws + 46137344);   // 4 MB   [B,S,NG,HD]
    __hip_bfloat16* vTB = (__hip_bfloat16*)(ws + 50331648);   // 4 MB   [B,NG,HD,S]
    float* Mf           = (float*)(ws + 54525952);            // 16 KB  mask additive term
    float* biasC        = (float*)(ws + 54542336);            // 12 KB  bias concat [3072]

    hipFuncSetAttribute((const void*)gemm_qkv3,
                        hipFuncAttributeMaxDynamicSharedMemorySize, 114688);
    hipFuncSetAttribute((const void*)attn,
                        hipFuncAttributeMaxDynamicSharedMemorySize, 83968);

    cvt_all<<<7168, 256, 0, stream>>>(hs, Wq, Wk, Wv, amask, bq, bk, bv,
                                      hsB, WqB, WkB, WvB, Mf, biasC);
    gemm_qkv3<<<256, 512, 114688, stream>>>(hsB, WqB, biasC, qB, kB, vTB);
    attn<<<256, 512, 83968, stream>>>(qB, kB, vTB, Mf, out);
}